// Round 2
// 25412.404 us; speedup vs baseline: 2.1973x; 2.1973x over previous
//
#include <hip/hip_runtime.h>
#include <math.h>

#define KBEAM 10
#define TSTEPS 70
#define EOS_TOK 2
#define PAD_TOK 0
#define START_TOK 1
#define EDIM 1024
#define HDIM 1024
#define VOCAB 32000
#define SLEN 128
#define NEGF (-1000000000.0f)
#define TOKW (TSTEPS + 1)   // 71

__device__ inline float wsum(float v) {
#pragma unroll
  for (int m = 32; m; m >>= 1) v += __shfl_xor(v, m, 64);
  return v;
}
__device__ inline float sigmoidf(float x) { return 1.0f / (1.0f + expf(-x)); }
// jax.lax.top_k ordering: larger value first; ties -> lower flat index
__device__ inline bool better(float v1, int i1, float v2, int i2) {
  return (v1 > v2) || (v1 == v2 && i1 < i2);
}

// ---------------- init ----------------
__global__ __launch_bounds__(256) void init_kernel(
    const float* __restrict__ h0, const float* __restrict__ c0,
    int* __restrict__ tokA, float* __restrict__ scores, int* __restrict__ finished,
    float* __restrict__ h_cur, float* __restrict__ c_cur, float* __restrict__ prev_cur) {
  int tid = threadIdx.x;
  for (int i = tid; i < KBEAM * TOKW; i += 256)
    tokA[i] = (i % TOKW == 0) ? START_TOK : PAD_TOK;
  if (tid < KBEAM) { scores[tid] = (tid == 0) ? 0.f : NEGF; finished[tid] = 0; }
  for (int i = tid; i < KBEAM * HDIM; i += 256) {
    int e = i & (HDIM - 1);
    h_cur[i] = h0[e]; c_cur[i] = c0[e]; prev_cur[i] = 0.f;
  }
}

// ---------------- keys = enc @ W_attproj^T : (S,H). One wave per output col j. ----------------
__global__ __launch_bounds__(256) void keys_kernel(
    const float* __restrict__ enc, const float* __restrict__ Wap, float* __restrict__ keys) {
  int j = (blockIdx.x * blockDim.x + threadIdx.x) >> 6;  // 0..1023
  int lane = threadIdx.x & 63;
  float w[32];
#pragma unroll
  for (int m = 0; m < 32; ++m) w[m] = Wap[(size_t)j * 2048 + m * 64 + lane];
  for (int s = 0; s < SLEN; ++s) {
    float a = 0.f;
#pragma unroll
    for (int m = 0; m < 32; ++m) a += w[m] * enc[(size_t)s * 2048 + m * 64 + lane];
    float r = wsum(a);
    if (lane == 0) keys[(size_t)s * 1024 + j] = r;
  }
}

// ---------------- gates = x@W_ih^T + b_ih + h@W_hh^T + b_hh : (K,4096). Wave per j. ----------------
// W_ih (4096, 2048): cols [0,1024)=emb[last], [1024,2048)=prevOut. W_hh (4096,1024).
// float4 everywhere: 132 vec loads/wave instead of 528 scalar.
__global__ __launch_bounds__(256) void gates_kernel(
    const float* __restrict__ emb, const float* __restrict__ prev,
    const float* __restrict__ h, const float* __restrict__ W_ih,
    const float* __restrict__ b_ih, const float* __restrict__ W_hh,
    const float* __restrict__ b_hh, const int* __restrict__ tok, int t,
    float* __restrict__ gates) {
  int j = (blockIdx.x * blockDim.x + threadIdx.x) >> 6;  // 0..4095
  int lane = threadIdx.x & 63;
  int last[KBEAM];
#pragma unroll
  for (int k = 0; k < KBEAM; ++k) last[k] = tok[k * TOKW + t];
  float acc[KBEAM];
#pragma unroll
  for (int k = 0; k < KBEAM; ++k) acc[k] = 0.f;

  const float4* wih4 = (const float4*)(W_ih + (size_t)j * 2048);
  const float4* whh4 = (const float4*)(W_hh + (size_t)j * 1024);
  const float4* emb4 = (const float4*)emb;
  const float4* prev4 = (const float4*)prev;
  const float4* h4 = (const float4*)h;

#pragma unroll
  for (int m = 0; m < 4; ++m) {            // emb part, f4 idx [0,256)
    int e = m * 64 + lane;
    float4 w = wih4[e];
#pragma unroll
    for (int k = 0; k < KBEAM; ++k) {
      float4 x = emb4[(size_t)last[k] * 256 + e];
      acc[k] += w.x * x.x; acc[k] += w.y * x.y; acc[k] += w.z * x.z; acc[k] += w.w * x.w;
    }
  }
#pragma unroll
  for (int m = 0; m < 4; ++m) {            // prevOut part, f4 idx [256,512)
    int e = m * 64 + lane;
    float4 w = wih4[256 + e];
#pragma unroll
    for (int k = 0; k < KBEAM; ++k) {
      float4 x = prev4[k * 256 + e];
      acc[k] += w.x * x.x; acc[k] += w.y * x.y; acc[k] += w.z * x.z; acc[k] += w.w * x.w;
    }
  }
#pragma unroll
  for (int m = 0; m < 4; ++m) {            // h part
    int e = m * 64 + lane;
    float4 w = whh4[e];
#pragma unroll
    for (int k = 0; k < KBEAM; ++k) {
      float4 x = h4[k * 256 + e];
      acc[k] += w.x * x.x; acc[k] += w.y * x.y; acc[k] += w.z * x.z; acc[k] += w.w * x.w;
    }
  }
#pragma unroll
  for (int k = 0; k < KBEAM; ++k) {
    float r = wsum(acc[k]);
    if (lane == 0) gates[k * 4096 + j] = r + b_ih[j] + b_hh[j];
  }
}

// ---------------- LSTM elementwise + attention + ctx. One block (256 thr) per beam. ----------------
// e[s] computed wave-parallel with COALESCED keys reads (was: serial dot with
// 64-line-scatter loads -> ~65K line transactions/wave).
__global__ __launch_bounds__(256) void attn_kernel(
    const float* __restrict__ gates, const float* __restrict__ c_cur,
    const float* __restrict__ keys, const float* __restrict__ enc,
    const int* __restrict__ src_len,
    float* __restrict__ h_new, float* __restrict__ c_new, float* __restrict__ ctx) {
  __shared__ float hn[HDIM];
  __shared__ float esm[SLEN];
  __shared__ float red[SLEN];
  int k = blockIdx.x, tid = threadIdx.x;

  // LSTM elementwise, float4: thread handles i = tid*4 .. tid*4+3
  {
    const float4* g4 = (const float4*)(gates + (size_t)k * 4096);
    float4 gi = g4[tid];
    float4 gf = g4[256 + tid];
    float4 gg = g4[512 + tid];
    float4 go = g4[768 + tid];
    float4 cc = ((const float4*)(c_cur + (size_t)k * HDIM))[tid];
    float4 cn, hv;
    cn.x = sigmoidf(gf.x) * cc.x + sigmoidf(gi.x) * tanhf(gg.x); hv.x = sigmoidf(go.x) * tanhf(cn.x);
    cn.y = sigmoidf(gf.y) * cc.y + sigmoidf(gi.y) * tanhf(gg.y); hv.y = sigmoidf(go.y) * tanhf(cn.y);
    cn.z = sigmoidf(gf.z) * cc.z + sigmoidf(gi.z) * tanhf(gg.z); hv.z = sigmoidf(go.z) * tanhf(cn.z);
    cn.w = sigmoidf(gf.w) * cc.w + sigmoidf(gi.w) * tanhf(gg.w); hv.w = sigmoidf(go.w) * tanhf(cn.w);
    ((float4*)(c_new + (size_t)k * HDIM))[tid] = cn;
    ((float4*)(h_new + (size_t)k * HDIM))[tid] = hv;
    ((float4*)hn)[tid] = hv;
  }
  __syncthreads();

  // e[s] = keys[s,:] . h_new — wave w handles s in [w*32, w*32+32), lane-strided dot + wsum.
  int sl = src_len[0];
  int w = tid >> 6, lane = tid & 63;
  float hr[16];
#pragma unroll
  for (int m = 0; m < 16; ++m) hr[m] = hn[m * 64 + lane];   // 2-way bank alias = free
  for (int n = 0; n < 32; ++n) {
    int s = w * 32 + n;
    const float* kr = keys + (size_t)s * 1024;
    float p = 0.f;
#pragma unroll
    for (int m = 0; m < 16; ++m) p += kr[m * 64 + lane] * hr[m];
    float r = wsum(p);
    if (lane == 0) esm[s] = (s >= sl) ? NEGF : r;
  }
  __syncthreads();

  // max via LDS tree over 128 (kept identical)
  if (tid < SLEN) red[tid] = esm[tid];
  __syncthreads();
  for (int off = 64; off >= 1; off >>= 1) {
    if (tid < off) red[tid] = fmaxf(red[tid], red[tid + off]);
    __syncthreads();
  }
  float mx = red[0];
  __syncthreads();
  if (tid < SLEN) { esm[tid] = expf(esm[tid] - mx); red[tid] = esm[tid]; }
  __syncthreads();
  for (int off = 64; off >= 1; off >>= 1) {
    if (tid < off) red[tid] = red[tid] + red[tid + off];
    __syncthreads();
  }
  float inv = 1.0f / red[0];
  __syncthreads();

  // ctx[k, :] = sum_s alpha[s] * enc[s, :] — float4, thread owns f4 cols tid and tid+256.
  const float4* enc4 = (const float4*)enc;
  float4 a0 = make_float4(0.f, 0.f, 0.f, 0.f);
  float4 a1 = make_float4(0.f, 0.f, 0.f, 0.f);
  for (int s = 0; s < SLEN; ++s) {
    float a = esm[s] * inv;
    float4 e0 = enc4[(size_t)s * 512 + tid];
    float4 e1 = enc4[(size_t)s * 512 + 256 + tid];
    a0.x += a * e0.x; a0.y += a * e0.y; a0.z += a * e0.z; a0.w += a * e0.w;
    a1.x += a * e1.x; a1.y += a * e1.y; a1.z += a * e1.z; a1.w += a * e1.w;
  }
  ((float4*)(ctx + (size_t)k * 2048))[tid] = a0;
  ((float4*)(ctx + (size_t)k * 2048))[256 + tid] = a1;
}

// ---------------- out = tanh([ctx,h_new] @ W_comb^T) : (K,1024). Wave per j, float4. ----------------
__global__ __launch_bounds__(256) void comb_kernel(
    const float* __restrict__ ctx, const float* __restrict__ h_new,
    const float* __restrict__ Wc, float* __restrict__ outb) {
  int j = (blockIdx.x * blockDim.x + threadIdx.x) >> 6;  // 0..1023
  int lane = threadIdx.x & 63;
  float acc[KBEAM];
#pragma unroll
  for (int k = 0; k < KBEAM; ++k) acc[k] = 0.f;
  const float4* wr4 = (const float4*)(Wc + (size_t)j * 3072);
  const float4* ctx4 = (const float4*)ctx;
  const float4* h4 = (const float4*)h_new;
#pragma unroll
  for (int m = 0; m < 8; ++m) {            // ctx part (512 f4)
    int e = m * 64 + lane;
    float4 w = wr4[e];
#pragma unroll
    for (int k = 0; k < KBEAM; ++k) {
      float4 x = ctx4[k * 512 + e];
      acc[k] += w.x * x.x; acc[k] += w.y * x.y; acc[k] += w.z * x.z; acc[k] += w.w * x.w;
    }
  }
#pragma unroll
  for (int m = 0; m < 4; ++m) {            // h_new part (256 f4)
    int e = m * 64 + lane;
    float4 w = wr4[512 + e];
#pragma unroll
    for (int k = 0; k < KBEAM; ++k) {
      float4 x = h4[k * 256 + e];
      acc[k] += w.x * x.x; acc[k] += w.y * x.y; acc[k] += w.z * x.z; acc[k] += w.w * x.w;
    }
  }
#pragma unroll
  for (int k = 0; k < KBEAM; ++k) {
    float r = wsum(acc[k]);
    if (lane == 0) outb[k * 1024 + j] = tanhf(r);
  }
}

// ---------------- logits = out @ W_vocab^T : (K,V). Wave per v, float4. ----------------
__global__ __launch_bounds__(256) void vocab_kernel(
    const float* __restrict__ outb, const float* __restrict__ Wv,
    float* __restrict__ logits) {
  int v = (blockIdx.x * blockDim.x + threadIdx.x) >> 6;  // 0..31999
  int lane = threadIdx.x & 63;
  float acc[KBEAM];
#pragma unroll
  for (int k = 0; k < KBEAM; ++k) acc[k] = 0.f;
  const float4* wr4 = (const float4*)(Wv + (size_t)v * 1024);
  const float4* ob4 = (const float4*)outb;
#pragma unroll
  for (int m = 0; m < 4; ++m) {
    int e = m * 64 + lane;
    float4 w = wr4[e];
#pragma unroll
    for (int k = 0; k < KBEAM; ++k) {
      float4 x = ob4[k * 256 + e];
      acc[k] += w.x * x.x; acc[k] += w.y * x.y; acc[k] += w.z * x.z; acc[k] += w.w * x.w;
    }
  }
#pragma unroll
  for (int k = 0; k < KBEAM; ++k) {
    float r = wsum(acc[k]);
    if (lane == 0) logits[(size_t)k * VOCAB + v] = r;
  }
}

// ---------------- per-row log-softmax + row top-10: SINGLE pass, per-thread reg top-10,
// then LDS tree-merge of 256 sorted lists. mx/logZ computation bitwise-identical to before.
__global__ __launch_bounds__(256) void rowtop_kernel(
    const float* __restrict__ logits, const float* __restrict__ scores,
    const int* __restrict__ finished,
    float* __restrict__ rt_val, int* __restrict__ rt_idx) {
  int k = blockIdx.x, tid = threadIdx.x;
  const float* lg = logits + (size_t)k * VOCAB;
  __shared__ float red[256];
  __shared__ float sv[256 * 10];
  __shared__ int si[256 * 10];

  // max (identical order to previous version)
  float m = -3.4e38f;
  for (int v = tid; v < VOCAB; v += 256) m = fmaxf(m, lg[v]);
  red[tid] = m;
  __syncthreads();
  for (int off = 128; off >= 1; off >>= 1) {
    if (tid < off) red[tid] = fmaxf(red[tid], red[tid + off]);
    __syncthreads();
  }
  float mx = red[0];
  __syncthreads();

  // sum exp (identical order to previous version)
  float s = 0.f;
  for (int v = tid; v < VOCAB; v += 256) s += expf(lg[v] - mx);
  red[tid] = s;
  __syncthreads();
  for (int off = 128; off >= 1; off >>= 1) {
    if (tid < off) red[tid] = red[tid] + red[tid + off];
    __syncthreads();
  }
  float logZ = logf(red[0]);
  __syncthreads();

  bool fin = finished[k] != 0;
  float sk = scores[k];

  // single-pass per-thread top-10 (register-resident, static indexing)
  float lv[10]; int li[10];
#pragma unroll
  for (int i = 0; i < 10; ++i) { lv[i] = -3.4e38f; li[i] = 0x7fffffff; }
  for (int v = tid; v < VOCAB; v += 256) {
    float val;
    if (fin) {
      val = sk + ((v == PAD_TOK) ? 0.f : NEGF);
    } else {
      float lp = (lg[v] - mx) - logZ;
      val = sk + lp;
    }
    if (better(val, v, lv[9], li[9])) {
      lv[9] = val; li[9] = v;
#pragma unroll
      for (int p = 9; p > 0; --p) {
        if (better(lv[p], li[p], lv[p - 1], li[p - 1])) {
          float tv = lv[p]; lv[p] = lv[p - 1]; lv[p - 1] = tv;
          int ti = li[p]; li[p] = li[p - 1]; li[p - 1] = ti;
        }
      }
    }
  }
#pragma unroll
  for (int i = 0; i < 10; ++i) { sv[tid * 10 + i] = lv[i]; si[tid * 10 + i] = li[i]; }
  __syncthreads();

  // tree-merge 256 sorted-desc lists -> list 0.
  for (int off = 128; off >= 1; off >>= 1) {
    if (tid < off) {
      int ia = 0, ib = 0;
      float ov[10]; int oi[10];
#pragma unroll
      for (int i = 0; i < 10; ++i) {
        float av = sv[tid * 10 + ia];        int aii = si[tid * 10 + ia];
        float bv = sv[(tid + off) * 10 + ib]; int bii = si[(tid + off) * 10 + ib];
        if (better(av, aii, bv, bii)) { ov[i] = av; oi[i] = aii; ++ia; }
        else                         { ov[i] = bv; oi[i] = bii; ++ib; }
      }
#pragma unroll
      for (int i = 0; i < 10; ++i) { sv[tid * 10 + i] = ov[i]; si[tid * 10 + i] = oi[i]; }
    }
    __syncthreads();
  }
  if (tid < 10) {
    rt_val[k * 10 + tid] = sv[tid];
    rt_idx[k * 10 + tid] = k * VOCAB + si[tid];
  }
}

// ---------------- final merge of 100 candidates + beam-state update ----------------
__global__ __launch_bounds__(256) void merge_kernel(
    const float* __restrict__ rt_val, const int* __restrict__ rt_idx,
    float* __restrict__ scores, int* __restrict__ finished,
    const int* __restrict__ tok_cur, int* __restrict__ tok_nxt, int t,
    const float* __restrict__ h_new, const float* __restrict__ c_new,
    const float* __restrict__ outb,
    float* __restrict__ h_cur, float* __restrict__ c_cur, float* __restrict__ prev_cur) {
  __shared__ float wv[10];
  __shared__ int wrow[10], wcol[10], ofin[10];
  __shared__ float cv[KBEAM * 10];
  __shared__ int ci[KBEAM * 10];
  int tid = threadIdx.x;
  if (tid < KBEAM) ofin[tid] = finished[tid];
  if (tid < KBEAM * 10) { cv[tid] = rt_val[tid]; ci[tid] = rt_idx[tid]; }  // parallel stage
  __syncthreads();
  if (tid == 0) {
    float bv[10]; int bi[10];
#pragma unroll
    for (int i = 0; i < 10; ++i) { bv[i] = -3.4e38f; bi[i] = 0x7fffffff; }
    for (int i = 0; i < KBEAM * 10; ++i) {
      float v = cv[i]; int g = ci[i];
      if (better(v, g, bv[9], bi[9])) {
        bv[9] = v; bi[9] = g;
#pragma unroll
        for (int p = 9; p > 0; --p) {
          if (better(bv[p], bi[p], bv[p - 1], bi[p - 1])) {
            float tv = bv[p]; bv[p] = bv[p - 1]; bv[p - 1] = tv;
            int ti = bi[p]; bi[p] = bi[p - 1]; bi[p - 1] = ti;
          }
        }
      }
    }
#pragma unroll
    for (int i = 0; i < 10; ++i) { wv[i] = bv[i]; wrow[i] = bi[i] / VOCAB; wcol[i] = bi[i] % VOCAB; }
  }
  __syncthreads();
  if (tid < KBEAM) {
    scores[tid] = wv[tid];
    finished[tid] = (ofin[wrow[tid]] || (wcol[tid] == EOS_TOK)) ? 1 : 0;
  }
  for (int i = tid; i < KBEAM * TOKW; i += 256) {
    int kk = i / TOKW, j = i % TOKW;
    tok_nxt[i] = (j == t + 1) ? wcol[kk] : tok_cur[wrow[kk] * TOKW + j];
  }
  // beam-state gather, float4 (2560 f4 per array)
  const float4* h4n = (const float4*)h_new;
  const float4* c4n = (const float4*)c_new;
  const float4* o4 = (const float4*)outb;
  float4* h4c = (float4*)h_cur;
  float4* c4c = (float4*)c_cur;
  float4* p4c = (float4*)prev_cur;
  for (int i = tid; i < KBEAM * 256; i += 256) {
    int kk = i >> 8, e = i & 255;
    int r = wrow[kk];
    h4c[i] = h4n[r * 256 + e];
    c4c[i] = c4n[r * 256 + e];
    p4c[i] = o4[r * 256 + e];
  }
}

// ---------------- write output (tokens as float values, then scores) ----------------
__global__ __launch_bounds__(256) void writeout_kernel(
    const int* __restrict__ tok, const float* __restrict__ scores, float* __restrict__ dout) {
  int tid = threadIdx.x;
  for (int i = tid; i < KBEAM * TOKW; i += 256) dout[i] = (float)tok[i];
  if (tid < KBEAM) dout[KBEAM * TOKW + tid] = scores[tid];
}

extern "C" void kernel_launch(void* const* d_in, const int* in_sizes, int n_in,
                              void* d_out, int out_size, void* d_ws, size_t ws_size,
                              hipStream_t stream) {
  const float* enc  = (const float*)d_in[0];
  const float* h0   = (const float*)d_in[1];
  const float* c0   = (const float*)d_in[2];
  const float* emb  = (const float*)d_in[3];
  const float* W_ih = (const float*)d_in[4];
  const float* b_ih = (const float*)d_in[5];
  const float* W_hh = (const float*)d_in[6];
  const float* b_hh = (const float*)d_in[7];
  const float* Wap  = (const float*)d_in[8];
  const float* Wc   = (const float*)d_in[9];
  const float* Wv   = (const float*)d_in[10];
  const int* src_len = (const int*)d_in[11];

  char* ws = (char*)d_ws;
  size_t off = 0;
  auto alloc = [&](size_t bytes) -> void* {
    void* p = ws + off;
    off += (bytes + 255) & ~(size_t)255;
    return p;
  };
  float* keys     = (float*)alloc((size_t)SLEN * HDIM * 4);
  float* gates    = (float*)alloc((size_t)KBEAM * 4096 * 4);
  float* h_cur    = (float*)alloc((size_t)KBEAM * HDIM * 4);
  float* c_cur    = (float*)alloc((size_t)KBEAM * HDIM * 4);
  float* prev_cur = (float*)alloc((size_t)KBEAM * HDIM * 4);
  float* h_new    = (float*)alloc((size_t)KBEAM * HDIM * 4);
  float* c_new    = (float*)alloc((size_t)KBEAM * HDIM * 4);
  float* ctx      = (float*)alloc((size_t)KBEAM * 2048 * 4);
  float* outb     = (float*)alloc((size_t)KBEAM * HDIM * 4);
  float* logits   = (float*)alloc((size_t)KBEAM * VOCAB * 4);
  float* rt_val   = (float*)alloc((size_t)KBEAM * 10 * 4);
  int*   rt_idx   = (int*)  alloc((size_t)KBEAM * 10 * 4);
  int*   tokA     = (int*)  alloc((size_t)KBEAM * TOKW * 4);
  int*   tokB     = (int*)  alloc((size_t)KBEAM * TOKW * 4);
  float* scores   = (float*)alloc((size_t)KBEAM * 4);
  int*   finished = (int*)  alloc((size_t)KBEAM * 4);
  (void)ws_size; (void)in_sizes; (void)n_in; (void)out_size;

  init_kernel<<<1, 256, 0, stream>>>(h0, c0, tokA, scores, finished, h_cur, c_cur, prev_cur);
  keys_kernel<<<256, 256, 0, stream>>>(enc, Wap, keys);       // 1024 waves = 1024 cols

  int* cur = tokA;
  int* nxt = tokB;
  for (int t = 0; t < TSTEPS; ++t) {
    gates_kernel<<<1024, 256, 0, stream>>>(emb, prev_cur, h_cur, W_ih, b_ih, W_hh, b_hh, cur, t, gates);
    attn_kernel<<<KBEAM, 256, 0, stream>>>(gates, c_cur, keys, enc, src_len, h_new, c_new, ctx);
    comb_kernel<<<256, 256, 0, stream>>>(ctx, h_new, Wc, outb);
    vocab_kernel<<<8000, 256, 0, stream>>>(outb, Wv, logits);
    rowtop_kernel<<<KBEAM, 256, 0, stream>>>(logits, scores, finished, rt_val, rt_idx);
    merge_kernel<<<1, 256, 0, stream>>>(rt_val, rt_idx, scores, finished, cur, nxt, t,
                                        h_new, c_new, outb, h_cur, c_cur, prev_cur);
    int* tmp = cur; cur = nxt; nxt = tmp;
  }
  writeout_kernel<<<1, 256, 0, stream>>>(cur, scores, (float*)d_out);
}